// Round 3
// baseline (415.873 us; speedup 1.0000x reference)
//
#include <hip/hip_runtime.h>

// SIREN MLP fused kernel, MI355X gfx950.
// [262144,3] -> sin(30(xW^T+b)) -> 4x sin(30(hW^T+b)) [256x256] -> linear -> [262144,3]
// All tensors fp32 (confirmed: out_npz=2.89MB=fp32*786432; threshold=2%*max|ref|).
// h kept as fp16 (MFMA operand), fp32 accumulate. Input dtype still detected
// on-device (cheap insurance); fp32 path is the expected one.

typedef _Float16 hf8 __attribute__((ext_vector_type(8)));
typedef _Float16 hf4 __attribute__((ext_vector_type(4)));
typedef float floatx4 __attribute__((ext_vector_type(4)));
typedef unsigned int uintx4 __attribute__((ext_vector_type(4)));
typedef unsigned short u16;

#define HID 256
#define NHID 4
#define BM 128          // points per block
#define THREADS 512     // 8 waves
#define C_REV 4.774648292756860f   // 30 / (2*pi)

__device__ __forceinline__ float bf2f(u16 u){
  union { unsigned int i; float f; } v; v.i = ((unsigned int)u) << 16; return v.f;
}
__device__ __forceinline__ float sin_rev(float r){
  float rr = r - rintf(r);          // reduce to [-0.5,0.5] revolutions
  float s;
  asm("v_sin_f32 %0, %1" : "=v"(s) : "v"(rr));   // HW sine takes revolutions
  return s;
}

template<bool F32>
__device__ __forceinline__ float ld1(const void* p, int i){
  return F32 ? ((const float*)p)[i] : bf2f(((const u16*)p)[i]);
}
template<bool F32>
__device__ __forceinline__ hf8 ld8h(const void* p, int i){
  hf8 o;
  if (F32){
    const float* f = (const float*)p + i;
    const floatx4 a = *(const floatx4*)f;
    const floatx4 b = *(const floatx4*)(f + 4);
#pragma unroll
    for (int e = 0; e < 4; ++e){ o[e] = (_Float16)a[e]; o[4+e] = (_Float16)b[e]; }
  } else {
    const uintx4 raw = *(const uintx4*)((const u16*)p + i);
#pragma unroll
    for (int j = 0; j < 4; ++j){
      union { unsigned int i; float f; } lo, hi;
      lo.i = raw[j] << 16;
      hi.i = raw[j] & 0xffff0000u;
      o[2*j]   = (_Float16)lo.f;
      o[2*j+1] = (_Float16)hi.f;
    }
  }
  return o;
}
template<bool F32>
__device__ __forceinline__ void ld8f(const void* p, int i, float* o){
  if (F32){
    const float* f = (const float*)p + i;
    const floatx4 a = *(const floatx4*)f;
    const floatx4 b = *(const floatx4*)(f + 4);
#pragma unroll
    for (int e = 0; e < 4; ++e){ o[e] = a[e]; o[4+e] = b[e]; }
  } else {
    const uintx4 raw = *(const uintx4*)((const u16*)p + i);
#pragma unroll
    for (int j = 0; j < 4; ++j){
      union { unsigned int i; float f; } lo, hi;
      lo.i = raw[j] << 16;
      hi.i = raw[j] & 0xffff0000u;
      o[2*j] = lo.f; o[2*j+1] = hi.f;
    }
  }
}

// swizzled element offset into [BM][HID] fp16 tile (XOR bits 3..5: conflict-free
// ds_read_b128; consistent for all 4/8-element aligned accesses since XOR bits
// never collide with intra-access offset bits)
__device__ __forceinline__ int hoff(int r, int c){
  return r*HID + (c ^ ((r & 7) << 3));
}

template<bool F32>
__device__ __forceinline__ void body(
    const void* __restrict__ x, const void* __restrict__ w_first,
    const void* __restrict__ b_first, const void* __restrict__ w_hidden,
    const void* __restrict__ b_hidden, const void* __restrict__ w_final,
    const void* __restrict__ b_final, float* __restrict__ out,
    _Float16* hb0, _Float16* hb1, float* wf)
{
  const int tid = threadIdx.x;
  const int blk = blockIdx.x;

  if (tid < HID){
    wf[tid*4+0] = ld1<F32>(w_first, tid*3+0) * C_REV;
    wf[tid*4+1] = ld1<F32>(w_first, tid*3+1) * C_REV;
    wf[tid*4+2] = ld1<F32>(w_first, tid*3+2) * C_REV;
    wf[tid*4+3] = ld1<F32>(b_first, tid)     * C_REV;
  }
  __syncthreads();

  // ---- first layer (K=3, VALU) ----
  {
    const int row = tid & (BM-1);
    const int cb  = (tid >> 7) * 64;
    const int gr  = blk*BM + row;
    const float x0 = ld1<F32>(x, gr*3+0);
    const float x1 = ld1<F32>(x, gr*3+1);
    const float x2 = ld1<F32>(x, gr*3+2);
#pragma unroll
    for (int g = 0; g < 8; ++g){
      hf8 hv;
#pragma unroll
      for (int e = 0; e < 8; ++e){
        const int j = cb + g*8 + e;
        const floatx4 w = *(const floatx4*)(&wf[j*4]);
        float r = w[3];
        r = fmaf(x0, w[0], r);
        r = fmaf(x1, w[1], r);
        r = fmaf(x2, w[2], r);
        hv[e] = (_Float16)sin_rev(r);
      }
      *(hf8*)(hb0 + hoff(row, cb + g*8)) = hv;
    }
  }
  __syncthreads();

  // ---- hidden layers: z^T = W.h^T via mfma_f32_16x16x32_f16 ----
  // wave owns 32 output features; A = W rows in regs (m = l&15, k-chunk = (l>>4)*8);
  // B = h^T from LDS (n = l&15, same k map -> any k-permutation cancels).
  // D: reg g -> feature (l>>4)*4+g, col -> point l&15  [m89-verified layout].
  const int wv  = tid >> 6;
  const int l   = tid & 63;
  const int l15 = l & 15;
  const int l4  = l >> 4;

  const _Float16* rb = hb0;
  _Float16*       wb = hb1;
  for (int L = 0; L < NHID; ++L){
    hf8   wfr[2][8];
    float bC[2][4];
#pragma unroll
    for (int m2 = 0; m2 < 2; ++m2){
      const int jrow  = wv*32 + m2*16 + l15;
      const int wbase = L*HID*HID + jrow*HID + l4*8;
#pragma unroll
      for (int k = 0; k < 8; ++k)
        wfr[m2][k] = ld8h<F32>(w_hidden, wbase + k*32);
      const int j0 = wv*32 + m2*16 + l4*4;
#pragma unroll
      for (int g = 0; g < 4; ++g)
        bC[m2][g] = ld1<F32>(b_hidden, L*HID + j0 + g) * C_REV;
    }

    for (int np = 0; np < 8; ++np){
      const int r = np*16 + l15;
      hf8 bh[8];
#pragma unroll
      for (int k = 0; k < 8; ++k)
        bh[k] = *(const hf8*)(rb + hoff(r, k*32 + l4*8));
      floatx4 acc0 = {0.f,0.f,0.f,0.f};
      floatx4 acc1 = {0.f,0.f,0.f,0.f};
#pragma unroll
      for (int k = 0; k < 8; ++k){
        acc0 = __builtin_amdgcn_mfma_f32_16x16x32_f16(wfr[0][k], bh[k], acc0, 0, 0, 0);
        acc1 = __builtin_amdgcn_mfma_f32_16x16x32_f16(wfr[1][k], bh[k], acc1, 0, 0, 0);
      }
#pragma unroll
      for (int m2 = 0; m2 < 2; ++m2){
        const floatx4 z = m2 ? acc1 : acc0;
        hf4 hv;
#pragma unroll
        for (int g = 0; g < 4; ++g)
          hv[g] = (_Float16)sin_rev(fmaf(z[g], C_REV, bC[m2][g]));
        const int jb = wv*32 + m2*16 + l4*4;
        *(hf4*)(wb + hoff(r, jb)) = hv;
      }
    }
    _Float16* t = (_Float16*)rb; rb = wb; wb = t;
    __syncthreads();
  }
  // after 4 layers, h is back in hb0 (== rb)

  // ---- final linear (fp32 out) ----
  {
    const int row = tid >> 2;
    const int q   = tid & 3;
    float s0 = 0.f, s1 = 0.f, s2 = 0.f;
#pragma unroll
    for (int i = 0; i < 8; ++i){
      const int c = q*64 + i*8;
      const hf8 hv = *(const hf8*)(rb + hoff(row, c));
      float w0v[8], w1v[8], w2v[8];
      ld8f<F32>(w_final, 0*HID + c, w0v);
      ld8f<F32>(w_final, 1*HID + c, w1v);
      ld8f<F32>(w_final, 2*HID + c, w2v);
#pragma unroll
      for (int e = 0; e < 8; ++e){
        const float h = (float)hv[e];
        s0 = fmaf(h, w0v[e], s0);
        s1 = fmaf(h, w1v[e], s1);
        s2 = fmaf(h, w2v[e], s2);
      }
    }
    s0 += __shfl_xor(s0, 1); s0 += __shfl_xor(s0, 2);
    s1 += __shfl_xor(s1, 1); s1 += __shfl_xor(s1, 2);
    s2 += __shfl_xor(s2, 1); s2 += __shfl_xor(s2, 2);
    if (q == 0){
      const float SENT = F32 ? 7777.0f : 4444.0f;   // NaN diagnosis via absmax
      float r0 = s0 + ld1<F32>(b_final, 0);
      float r1 = s1 + ld1<F32>(b_final, 1);
      float r2 = s2 + ld1<F32>(b_final, 2);
      if (!(fabsf(r0) < 1e30f)) r0 = SENT;
      if (!(fabsf(r1) < 1e30f)) r1 = SENT;
      if (!(fabsf(r2) < 1e30f)) r2 = SENT;
      const int gr = blk*BM + row;
      out[gr*3+0] = r0;
      out[gr*3+1] = r1;
      out[gr*3+2] = r2;
    }
  }
}

__global__ __launch_bounds__(THREADS) void siren_kernel(
    const void* __restrict__ x, const void* __restrict__ w_first,
    const void* __restrict__ b_first, const void* __restrict__ w_hidden,
    const void* __restrict__ b_hidden, const void* __restrict__ w_final,
    const void* __restrict__ b_final, float* __restrict__ out)
{
  __shared__ __align__(16) _Float16 hbuf[2][BM*HID];   // 128 KB
  __shared__ __align__(16) float wf[HID*4];            // 4 KB

  // dtype detect (wave-uniform, deterministic): bf16 coords all decode |v|<=1;
  // fp32 low-half words decode >1 somewhere with P ~= 1.
  const u16* xu = (const u16*)x;
  const float v = bf2f(xu[threadIdx.x & 63]);
  const bool bad = !(fabsf(v) <= 1.0f);
  const bool isf32 = (__ballot(bad) != 0ULL);

  if (isf32)
    body<true >(x, w_first, b_first, w_hidden, b_hidden, w_final, b_final, out,
                &hbuf[0][0], &hbuf[1][0], wf);
  else
    body<false>(x, w_first, b_first, w_hidden, b_hidden, w_final, b_final, out,
                &hbuf[0][0], &hbuf[1][0], wf);
}

extern "C" void kernel_launch(void* const* d_in, const int* in_sizes, int n_in,
                              void* d_out, int out_size, void* d_ws, size_t ws_size,
                              hipStream_t stream) {
  const int npts = in_sizes[0] / 3;
  const int grid = npts / BM;   // 2048
  hipLaunchKernelGGL(siren_kernel, dim3(grid), dim3(THREADS), 0, stream,
                     d_in[0], d_in[1], d_in[2], d_in[3], d_in[4], d_in[5], d_in[6],
                     (float*)d_out);
}

// Round 4
// 293.386 us; speedup vs baseline: 1.4175x; 1.4175x over previous
//
#include <hip/hip_runtime.h>

// SIREN MLP fused kernel, MI355X gfx950 — round 4.
// [262144,3] -> sin(30(xW^T+b)) -> 4x sin(30(hW^T+b)) [256x256] -> linear -> [262144,3]
// All global tensors fp32 (confirmed r3). h kept as fp16 (MFMA operand), fp32 accum.
// R4 changes vs R3 (latency-bound at 23% occupancy, 1 block/CU):
//   - BM 128->64: LDS 132->70 KB -> 2 blocks/CU, 4 waves/SIMD.
//   - prepass converts w_hidden+w_final to fp16 in d_ws: A-frags load as one
//     dwordx4, no per-layer cvt VALU, W fetch bytes halved.
//   - w_final staged in LDS (was 384 KB/block of redundant global reads).

typedef _Float16 hf8 __attribute__((ext_vector_type(8)));
typedef _Float16 hf4 __attribute__((ext_vector_type(4)));
typedef float floatx4 __attribute__((ext_vector_type(4)));
typedef unsigned short u16;

#define HID 256
#define NHID 4
#define BM 64           // points per block
#define THREADS 512     // 8 waves; wave w owns output features [32w, 32w+32)
#define NP (BM/16)      // 4 point-tiles per wave
#define C_REV 4.774648292756860f   // 30 / (2*pi)
#define WH_ELEMS (NHID*HID*HID)    // 262144
#define WS_HALVES (WH_ELEMS + 3*HID)

__device__ __forceinline__ float sin_rev(float r){
  float rr = r - rintf(r);                       // revolutions -> [-0.5, 0.5]
  float s;
  asm("v_sin_f32 %0, %1" : "=v"(s) : "v"(rr));   // HW sine takes revolutions
  return s;
}
__device__ __forceinline__ hf8 ld8h_f32(const float* f){
  const floatx4 a = *(const floatx4*)f;
  const floatx4 b = *(const floatx4*)(f + 4);
  hf8 o;
#pragma unroll
  for (int e = 0; e < 4; ++e){ o[e] = (_Float16)a[e]; o[4+e] = (_Float16)b[e]; }
  return o;
}
// swizzled element offset into [BM][HID] fp16 tile: XOR bits 3..5 break the
// 512B-row-stride bank pattern; never collides with intra-access bits (<=8 elems)
__device__ __forceinline__ int hoff(int r, int c){
  return r*HID + (c ^ ((r & 7) << 3));
}

// ---- prepass: w_hidden, w_final fp32 -> fp16 in ws ----
__global__ void prep_kernel(const float* __restrict__ wh,
                            const float* __restrict__ wfin,
                            _Float16* __restrict__ ws){
  const int i = blockIdx.x*256 + threadIdx.x;
  if (i < WH_ELEMS)            ws[i] = (_Float16)wh[i];
  else if (i < WS_HALVES)      ws[i] = (_Float16)wfin[i - WH_ELEMS];
}

template<bool WS>
__global__ __launch_bounds__(THREADS, 4) void siren_kernel(
    const float* __restrict__ x, const float* __restrict__ w_first,
    const float* __restrict__ b_first, const float* __restrict__ w_hidden,
    const float* __restrict__ b_hidden, const float* __restrict__ w_final,
    const float* __restrict__ b_final, const _Float16* __restrict__ wsh,
    float* __restrict__ out)
{
  __shared__ __align__(16) _Float16 hbuf[2][BM*HID];   // 64 KB double-buffered h
  __shared__ __align__(16) float    wf[HID*4];         // 4 KB first-layer (w0,w1,w2,b)*C_REV
  __shared__ __align__(16) _Float16 wfin[3*HID];       // 1.5 KB final-layer weights fp16

  const int tid = threadIdx.x;
  const int blk = blockIdx.x;

  // ---- stage first-layer weights (threads 0..255) and w_final (256..511) ----
  if (tid < HID){
    wf[tid*4+0] = w_first[tid*3+0] * C_REV;
    wf[tid*4+1] = w_first[tid*3+1] * C_REV;
    wf[tid*4+2] = w_first[tid*3+2] * C_REV;
    wf[tid*4+3] = b_first[tid]     * C_REV;
  } else {
    const int i0 = (tid - HID) * 3;
#pragma unroll
    for (int j = 0; j < 3; ++j){
      const int i = i0 + j;
      if (i < 3*HID) wfin[i] = WS ? wsh[WH_ELEMS + i] : (_Float16)w_final[i];
    }
  }
  __syncthreads();

  // ---- first layer (K=3, VALU): 64 rows x 8 col-strips of 32 ----
  {
    const int row = tid & (BM-1);
    const int cb  = (tid >> 6) * 32;
    const int gr  = blk*BM + row;
    const float x0 = x[gr*3+0];
    const float x1 = x[gr*3+1];
    const float x2 = x[gr*3+2];
#pragma unroll
    for (int g = 0; g < 4; ++g){
      hf8 hv;
#pragma unroll
      for (int e = 0; e < 8; ++e){
        const int j = cb + g*8 + e;
        const floatx4 w = *(const floatx4*)(&wf[j*4]);   // wave-uniform broadcast
        float r = w[3];
        r = fmaf(x0, w[0], r);
        r = fmaf(x1, w[1], r);
        r = fmaf(x2, w[2], r);
        hv[e] = (_Float16)sin_rev(r);
      }
      *(hf8*)(&hbuf[0][hoff(row, cb + g*8)]) = hv;
    }
  }
  __syncthreads();

  // ---- hidden layers: z^T = W.h^T via mfma_f32_16x16x32_f16 ----
  // A = W rows in regs (m=l&15, k-chunk=(l>>4)*8); B = h^T from LDS (same k map,
  // k-permutation cancels). D: reg g -> feature (l>>4)*4+g, col -> point l&15.
  const int wv  = tid >> 6;
  const int l   = tid & 63;
  const int l15 = l & 15;
  const int l4  = l >> 4;

  const _Float16* rb = &hbuf[0][0];
  _Float16*       wb = &hbuf[1][0];
  for (int L = 0; L < NHID; ++L){
    hf8   wfr[2][8];
    float bC[2][4];
#pragma unroll
    for (int m2 = 0; m2 < 2; ++m2){
      const int jrow  = wv*32 + m2*16 + l15;
      const int wbase = L*HID*HID + jrow*HID + l4*8;
#pragma unroll
      for (int k = 0; k < 8; ++k){
        if (WS) wfr[m2][k] = *(const hf8*)(wsh + wbase + k*32);   // one dwordx4
        else    wfr[m2][k] = ld8h_f32(w_hidden + wbase + k*32);
      }
      const int j0 = wv*32 + m2*16 + l4*4;
#pragma unroll
      for (int g = 0; g < 4; ++g)
        bC[m2][g] = b_hidden[L*HID + j0 + g] * C_REV;
    }

#pragma unroll
    for (int np = 0; np < NP; ++np){
      const int r = np*16 + l15;
      hf8 bh[8];
#pragma unroll
      for (int k = 0; k < 8; ++k)
        bh[k] = *(const hf8*)(rb + hoff(r, k*32 + l4*8));
      floatx4 acc0 = {0.f,0.f,0.f,0.f};
      floatx4 acc1 = {0.f,0.f,0.f,0.f};
#pragma unroll
      for (int k = 0; k < 8; ++k){
        acc0 = __builtin_amdgcn_mfma_f32_16x16x32_f16(wfr[0][k], bh[k], acc0, 0, 0, 0);
        acc1 = __builtin_amdgcn_mfma_f32_16x16x32_f16(wfr[1][k], bh[k], acc1, 0, 0, 0);
      }
#pragma unroll
      for (int m2 = 0; m2 < 2; ++m2){
        const floatx4 z = m2 ? acc1 : acc0;
        hf4 hv;
#pragma unroll
        for (int g = 0; g < 4; ++g)
          hv[g] = (_Float16)sin_rev(fmaf(z[g], C_REV, bC[m2][g]));
        const int jb = wv*32 + m2*16 + l4*4;
        *(hf4*)(wb + hoff(r, jb)) = hv;
      }
    }
    _Float16* t = (_Float16*)rb; rb = wb; wb = t;
    __syncthreads();
  }
  // after 4 layers, h is in hbuf[0] (== rb)

  // ---- final linear (fp32 out): 64 rows x 8-way K-split ----
  {
    const int row = tid >> 3;
    const int q   = tid & 7;
    float s0 = 0.f, s1 = 0.f, s2 = 0.f;
#pragma unroll
    for (int i = 0; i < 4; ++i){
      const int c = q*32 + i*8;
      const hf8 hv = *(const hf8*)(rb + hoff(row, c));
      const hf8 w0 = *(const hf8*)(&wfin[0*HID + c]);
      const hf8 w1 = *(const hf8*)(&wfin[1*HID + c]);
      const hf8 w2 = *(const hf8*)(&wfin[2*HID + c]);
#pragma unroll
      for (int e = 0; e < 8; ++e){
        const float h = (float)hv[e];
        s0 = fmaf(h, (float)w0[e], s0);
        s1 = fmaf(h, (float)w1[e], s1);
        s2 = fmaf(h, (float)w2[e], s2);
      }
    }
    s0 += __shfl_xor(s0, 1); s0 += __shfl_xor(s0, 2); s0 += __shfl_xor(s0, 4);
    s1 += __shfl_xor(s1, 1); s1 += __shfl_xor(s1, 2); s1 += __shfl_xor(s1, 4);
    s2 += __shfl_xor(s2, 1); s2 += __shfl_xor(s2, 2); s2 += __shfl_xor(s2, 4);
    if (q == 0){
      const int gr = blk*BM + row;
      out[gr*3+0] = s0 + b_final[0];
      out[gr*3+1] = s1 + b_final[1];
      out[gr*3+2] = s2 + b_final[2];
    }
  }
}

extern "C" void kernel_launch(void* const* d_in, const int* in_sizes, int n_in,
                              void* d_out, int out_size, void* d_ws, size_t ws_size,
                              hipStream_t stream) {
  const float* x        = (const float*)d_in[0];
  const float* w_first  = (const float*)d_in[1];
  const float* b_first  = (const float*)d_in[2];
  const float* w_hidden = (const float*)d_in[3];
  const float* b_hidden = (const float*)d_in[4];
  const float* w_final  = (const float*)d_in[5];
  const float* b_final  = (const float*)d_in[6];
  float* out = (float*)d_out;
  _Float16* wsh = (_Float16*)d_ws;

  const int npts = in_sizes[0] / 3;
  const int grid = npts / BM;   // 4096
  const bool use_ws = (ws_size >= (size_t)WS_HALVES * sizeof(_Float16));

  if (use_ws){
    const int pgrid = (WS_HALVES + 255) / 256;
    hipLaunchKernelGGL(prep_kernel, dim3(pgrid), dim3(256), 0, stream,
                       w_hidden, w_final, wsh);
    hipLaunchKernelGGL(siren_kernel<true>, dim3(grid), dim3(THREADS), 0, stream,
                       x, w_first, b_first, w_hidden, b_hidden, w_final, b_final,
                       wsh, out);
  } else {
    hipLaunchKernelGGL(siren_kernel<false>, dim3(grid), dim3(THREADS), 0, stream,
                       x, w_first, b_first, w_hidden, b_hidden, w_final, b_final,
                       wsh, out);
  }
}